// Round 3
// baseline (1899.701 us; speedup 1.0000x reference)
//
#include <hip/hip_runtime.h>

#define BATCH 32
#define NPTS  8192
#define DIM   64
#define KC    128
#define NITER 10
#define LN_EPS 1e-5f

// ---------------------------------------------------------------------------
// Precision strategy (round-2 lesson): all fp32 implementations of
//   d = (x2 + c2[k]) - 2*dot   computed IN FP32
// make CORRELATED rounding decisions on Voronoi-boundary points (the add/sub
// rounding at |d|~128 is a deterministic function of the values). Dropping x2
// or going fp64 decorrelates -> ~10x the boundary-flip damage (0.0957 vs the
// 4e-3 jax-np distance). So: formula-faithful fp32 distances; deterministic
// fp64 accumulation rounded to fp32 for center updates (~1e-7 from ref).
//
// ws: xn fp32 (64MB) | cen fp32 (1MB) | c2 fp32 (16KB)
// Partials live in d_out's soft region (fully overwritten by final_kernel):
//   part 512*8192 fp64 (33.5MB) | cntpart 512*128 fp32
// ---------------------------------------------------------------------------

__device__ __forceinline__ float dot64(const float4* __restrict__ xv,
                                       const float4* __restrict__ cp) {
    float d0 = 0.f, d1 = 0.f, d2 = 0.f, d3 = 0.f;
#pragma unroll
    for (int j = 0; j < 4; ++j) {
        float4 c0 = cp[4 * j + 0];
        float4 c1 = cp[4 * j + 1];
        float4 c2v = cp[4 * j + 2];
        float4 c3 = cp[4 * j + 3];
        float4 x0 = xv[4 * j + 0];
        float4 x1 = xv[4 * j + 1];
        float4 x2v = xv[4 * j + 2];
        float4 x3 = xv[4 * j + 3];
        d0 = fmaf(x0.w, c0.w, fmaf(x0.z, c0.z, fmaf(x0.y, c0.y, fmaf(x0.x, c0.x, d0))));
        d1 = fmaf(x1.w, c1.w, fmaf(x1.z, c1.z, fmaf(x1.y, c1.y, fmaf(x1.x, c1.x, d1))));
        d2 = fmaf(x2v.w, c2v.w, fmaf(x2v.z, c2v.z, fmaf(x2v.y, c2v.y, fmaf(x2v.x, c2v.x, d2))));
        d3 = fmaf(x3.w, c3.w, fmaf(x3.z, c3.z, fmaf(x3.y, c3.y, fmaf(x3.x, c3.x, d3))));
    }
    return (d0 + d1) + (d2 + d3);
}

__device__ __forceinline__ float sq64(const float4* __restrict__ xv) {
    float a0 = 0.f, a1 = 0.f, a2 = 0.f, a3 = 0.f;
#pragma unroll
    for (int j = 0; j < 16; ++j) {
        float4 t = xv[j];
        a0 = fmaf(t.x, t.x, a0);
        a1 = fmaf(t.y, t.y, a1);
        a2 = fmaf(t.z, t.z, a2);
        a3 = fmaf(t.w, t.w, a3);
    }
    return (a0 + a1) + (a2 + a3);
}

// One wave per row. Writes xn; first 128 rows per batch also seed cen + c2.
__global__ __launch_bounds__(256) void ln_kernel(const float* __restrict__ patches,
                                                 const float* __restrict__ gamma,
                                                 const float* __restrict__ beta,
                                                 float* __restrict__ xn,
                                                 float* __restrict__ cen,
                                                 float* __restrict__ c2) {
    int row = blockIdx.x * 4 + (threadIdx.x >> 6);
    int lane = threadIdx.x & 63;
    size_t base = (size_t)row * DIM + lane;
    float x = patches[base];

    float s = x;
#pragma unroll
    for (int m = 32; m >= 1; m >>= 1) s += __shfl_xor(s, m, 64);
    float mu = s * (1.0f / 64.0f);
    float dx = x - mu;

    float v = dx * dx;
#pragma unroll
    for (int m = 32; m >= 1; m >>= 1) v += __shfl_xor(v, m, 64);
    float var = v * (1.0f / 64.0f);

    float val = dx * (1.0f / sqrtf(var + LN_EPS)) * gamma[lane] + beta[lane];
    xn[base] = val;

    int n = row & (NPTS - 1);
    int b = row >> 13;  // NPTS = 8192 = 2^13
    if (n < KC) {
        cen[((size_t)(b * KC + n)) * DIM + lane] = val;
        float q = val * val;
#pragma unroll
        for (int m = 32; m >= 1; m >>= 1) q += __shfl_xor(q, m, 64);
        if (lane == 0) c2[b * KC + n] = q;
    }
}

// Thread per point: formula-faithful fp32 argmin, fp64 LDS accumulation,
// deterministic per-block partial flush (no global atomics, no memset).
__global__ __launch_bounds__(512) void assign_kernel(const float* __restrict__ xn,
                                                     const float* __restrict__ cen,
                                                     const float* __restrict__ c2,
                                                     double* __restrict__ part,
                                                     float* __restrict__ cntpart) {
    __shared__ double ls[KC * 65];
    __shared__ float lc[KC];
    for (int i = threadIdx.x; i < KC * 65; i += 512) ls[i] = 0.0;
    if (threadIdx.x < KC) lc[threadIdx.x] = 0.f;
    __syncthreads();

    int blk = blockIdx.x;
    int b = blk >> 4;  // 16 blocks per batch
    int p = b * NPTS + ((blk & 15) << 9) + threadIdx.x;

    const float4* xp = (const float4*)(xn + (size_t)p * DIM);
    float4 xv[16];
#pragma unroll
    for (int j = 0; j < 16; ++j) xv[j] = xp[j];
    float x2 = sq64(xv);

    const float4* cp = (const float4*)(cen + (size_t)b * KC * DIM);
    const float* c2p = c2 + b * KC;

    float best = 3.4e38f;
    int bi = 0;
#pragma unroll 2
    for (int k = 0; k < KC; ++k) {
        float dot = dot64(xv, cp + k * 16);
        float t = x2 + c2p[k];        // fp32, same op order as reference
        float d = t - 2.0f * dot;     // (2*dot exact; single rounding)
        if (d < best) { best = d; bi = k; }  // strict < == argmin first-index
    }

    double* dst = ls + bi * 65;
#pragma unroll
    for (int j = 0; j < 16; ++j) {
        atomicAdd(dst + 4 * j + 0, (double)xv[j].x);
        atomicAdd(dst + 4 * j + 1, (double)xv[j].y);
        atomicAdd(dst + 4 * j + 2, (double)xv[j].z);
        atomicAdd(dst + 4 * j + 3, (double)xv[j].w);
    }
    atomicAdd(&lc[bi], 1.0f);
    __syncthreads();

    double* gp = part + (size_t)blk * KC * DIM;
    for (int i = threadIdx.x; i < KC * DIM; i += 512) {
        int k = i >> 6, d = i & 63;
        gp[i] = ls[k * 65 + d];
    }
    if (threadIdx.x < KC) cntpart[blk * KC + threadIdx.x] = lc[threadIdx.x];
}

// One wave per (b,k): reduce 16 block partials, fp32 center + fp32 norm.
__global__ __launch_bounds__(256) void update_kernel(const double* __restrict__ part,
                                                     const float* __restrict__ cntpart,
                                                     float* __restrict__ cen,
                                                     float* __restrict__ c2) {
    int row = blockIdx.x * 4 + (threadIdx.x >> 6);  // b*KC + k
    int lane = threadIdx.x & 63;
    int b = row >> 7;
    int k = row & (KC - 1);

    double s = 0.0;
    float cnt = 0.f;
#pragma unroll
    for (int sub = 0; sub < 16; ++sub) {
        s += part[((size_t)(b * 16 + sub)) * KC * DIM + (size_t)k * DIM + lane];
        cnt += cntpart[(b * 16 + sub) * KC + k];
    }

    size_t idx = (size_t)row * DIM + lane;
    float old = cen[idx];
    float nc = (cnt > 0.f) ? ((float)s / cnt) : old;
    cen[idx] = nc;

    float q = nc * nc;
#pragma unroll
    for (int m = 32; m >= 1; m >>= 1) q += __shfl_xor(q, m, 64);
    if (lane == 0) c2[row] = q;
}

// Thread per point: pass 1 online min+denominator, pass 2 write. Same fp32
// distance formula as the assign step (keeps softmax args ref-correlated).
__global__ __launch_bounds__(512) void final_kernel(const float* __restrict__ xn,
                                                    const float* __restrict__ cen,
                                                    const float* __restrict__ c2,
                                                    float* __restrict__ soft) {
    int b = blockIdx.x >> 4;
    int p = b * NPTS + ((blockIdx.x & 15) << 9) + threadIdx.x;

    const float4* xp = (const float4*)(xn + (size_t)p * DIM);
    float4 xv[16];
#pragma unroll
    for (int j = 0; j < 16; ++j) xv[j] = xp[j];
    float x2 = sq64(xv);

    const float4* cp = (const float4*)(cen + (size_t)b * KC * DIM);
    const float* c2p = c2 + b * KC;

    // softmax(-d): online track m = max(-d), denom
    float m = -3.4e38f;
    float ssum = 0.f;
#pragma unroll 2
    for (int k = 0; k < KC; ++k) {
        float dot = dot64(xv, cp + k * 16);
        float t = x2 + c2p[k];
        float z = -(t - 2.0f * dot);
        if (z > m) {
            ssum = ssum * __expf(m - z) + 1.0f;
            m = z;
        } else {
            ssum += __expf(z - m);
        }
    }
    float rinv = 1.0f / ssum;

    float* op = soft + (size_t)p * KC;
#pragma unroll 2
    for (int k = 0; k < KC; ++k) {
        float dot = dot64(xv, cp + k * 16);
        float t = x2 + c2p[k];
        float z = -(t - 2.0f * dot);
        op[k] = __expf(z - m) * rinv;
    }
}

extern "C" void kernel_launch(void* const* d_in, const int* in_sizes, int n_in,
                              void* d_out, int out_size, void* d_ws, size_t ws_size,
                              hipStream_t stream) {
    (void)in_sizes; (void)n_in; (void)out_size; (void)ws_size;
    const float* patches = (const float*)d_in[0];
    const float* gamma = (const float*)d_in[1];
    const float* beta = (const float*)d_in[2];
    float* out = (float*)d_out;

    float* ws = (float*)d_ws;
    float* xn = ws;                                   // 16,777,216 f32
    float* cen = xn + (size_t)BATCH * NPTS * DIM;     // 262,144 f32
    float* c2 = cen + (size_t)BATCH * KC * DIM;       // 4,096 f32

    // Scratch partials in d_out's soft region (overwritten by final_kernel)
    float* soft = out + (size_t)BATCH * KC * DIM;
    double* part = (double*)soft;                     // 512*8192 f64
    float* cntpart = (float*)(part + (size_t)512 * KC * DIM);

    ln_kernel<<<BATCH * NPTS / 4, 256, 0, stream>>>(patches, gamma, beta, xn, cen, c2);

    for (int it = 0; it < NITER; ++it) {
        assign_kernel<<<BATCH * 16, 512, 0, stream>>>(xn, cen, c2, part, cntpart);
        update_kernel<<<BATCH * KC / 4, 256, 0, stream>>>(part, cntpart, cen, c2);
    }

    hipMemcpyAsync(out, cen, (size_t)BATCH * KC * DIM * sizeof(float),
                   hipMemcpyDeviceToDevice, stream);
    final_kernel<<<BATCH * 16, 512, 0, stream>>>(xn, cen, c2, soft);
}